// Round 1
// baseline (104.857 us; speedup 1.0000x reference)
//
#include <hip/hip_runtime.h>

#define NODES 100000
#define NTAG  10000
#define NE    4
#define ND    32
#define NB    524288

constexpr int TPB  = 256;      // threads per block
constexpr int NBLK = 2048;     // main-kernel blocks
constexpr int GPB  = TPB / 8;  // sample-groups per block (8 lanes per sample)

// ---- init: copy activate into out[1..], zero ws partials --------------------
__global__ __launch_bounds__(TPB) void init_kernel(const float* __restrict__ act,
                                                   float* __restrict__ out,
                                                   double* __restrict__ ws, int npart) {
    int i = blockIdx.x * TPB + threadIdx.x;
    if (i < NODES * NE) out[1 + i] = act[i];
    if (i < npart)      ws[i] = 0.0;
}

// ---- main: dists, argmin, scatter, loss partials ---------------------------
__global__ __launch_bounds__(TPB) void main_kernel(
    const float* __restrict__ tag_table, const float* __restrict__ node_tables,
    const int* __restrict__ pos_node, const int* __restrict__ pos_tag,
    const int* __restrict__ neg_node, const int* __restrict__ neg_tag,
    float* __restrict__ out, double* __restrict__ ws, int npart)
{
    const int g   = threadIdx.x & 7;   // lane within 8-lane sample group
    const int grp = threadIdx.x >> 3;  // group id within block
    double local = 0.0;

    const int total = 2 * NB;          // first NB = pos, next NB = neg
    for (int s = blockIdx.x * GPB + grp; s < total; s += NBLK * GPB) {
        const bool is_pos = (s < NB);
        const int  b    = is_pos ? s : s - NB;
        const int  node = is_pos ? pos_node[b] : neg_node[b];
        const int  tag  = is_pos ? pos_tag[b]  : neg_tag[b];

        // 8 lanes x float4 = one 128B row, fully coalesced per row
        const float4 t  = *(const float4*)(tag_table + (size_t)tag * ND + g * 4);
        const float4 n0 = *(const float4*)(node_tables + ((size_t)0 * NODES + node) * ND + g * 4);
        const float4 n1 = *(const float4*)(node_tables + ((size_t)1 * NODES + node) * ND + g * 4);
        const float4 n2 = *(const float4*)(node_tables + ((size_t)2 * NODES + node) * ND + g * 4);
        const float4 n3 = *(const float4*)(node_tables + ((size_t)3 * NODES + node) * ND + g * 4);

        // fp64 partial dots (minimize argmin-tie discrepancy vs fp32 reference)
        double p0 = (double)n0.x * t.x + (double)n0.y * t.y + (double)n0.z * t.z + (double)n0.w * t.w;
        double p1 = (double)n1.x * t.x + (double)n1.y * t.y + (double)n1.z * t.z + (double)n1.w * t.w;
        double p2 = (double)n2.x * t.x + (double)n2.y * t.y + (double)n2.z * t.z + (double)n2.w * t.w;
        double p3 = (double)n3.x * t.x + (double)n3.y * t.y + (double)n3.z * t.z + (double)n3.w * t.w;

        #pragma unroll
        for (int off = 1; off < 8; off <<= 1) {
            p0 += __shfl_xor(p0, off, 64);
            p1 += __shfl_xor(p1, off, 64);
            p2 += __shfl_xor(p2, off, 64);
            p3 += __shfl_xor(p3, off, 64);
        }

        // dist_e = -p_e; argmin(dist) first-occurrence == strict "p_e > best"
        double bestp = p0; int idx = 0;
        if (p1 > bestp) { bestp = p1; idx = 1; }
        if (p2 > bestp) { bestp = p2; idx = 2; }
        if (p3 > bestp) { bestp = p3; idx = 3; }

        // pos term: softplus(dist) ; neg term: softplus(-dist); dist = -bestp
        const float x  = (float)(is_pos ? -bestp : bestp);
        const float sp = fmaxf(x, 0.0f) + log1pf(expf(-fabsf(x)));

        if (g == 0) {
            local += (double)sp;
            if (is_pos) atomicAdd(out + 1 + (size_t)node * NE + idx, 1.0f);
        }
    }

    // wave butterfly (zeros from g!=0 lanes are harmless), then LDS, then ws
    #pragma unroll
    for (int off = 1; off < 64; off <<= 1) local += __shfl_xor(local, off, 64);

    __shared__ double sm[TPB / 64];
    if ((threadIdx.x & 63) == 0) sm[threadIdx.x >> 6] = local;
    __syncthreads();
    if (threadIdx.x == 0) {
        double tot = 0.0;
        #pragma unroll
        for (int w = 0; w < TPB / 64; ++w) tot += sm[w];
        atomicAdd(&ws[blockIdx.x & (npart - 1)], tot);
    }
}

// ---- final: reduce ws partials into out[0] ---------------------------------
__global__ __launch_bounds__(TPB) void final_kernel(const double* __restrict__ ws,
                                                    float* __restrict__ out, int npart) {
    __shared__ double sm[TPB];
    double v = 0.0;
    for (int i = threadIdx.x; i < npart; i += TPB) v += ws[i];
    sm[threadIdx.x] = v;
    __syncthreads();
    for (int s = TPB / 2; s > 0; s >>= 1) {
        if (threadIdx.x < s) sm[threadIdx.x] += sm[threadIdx.x + s];
        __syncthreads();
    }
    if (threadIdx.x == 0) out[0] = (float)sm[0];
}

extern "C" void kernel_launch(void* const* d_in, const int* in_sizes, int n_in,
                              void* d_out, int out_size, void* d_ws, size_t ws_size,
                              hipStream_t stream) {
    const float* tag_table   = (const float*)d_in[0];
    const float* node_tables = (const float*)d_in[1];
    const float* activate    = (const float*)d_in[2];
    const int*   pos_node    = (const int*)d_in[3];
    const int*   pos_tag     = (const int*)d_in[4];
    const int*   neg_node    = (const int*)d_in[5];
    const int*   neg_tag     = (const int*)d_in[6];
    float*  out = (float*)d_out;
    double* ws  = (double*)d_ws;

    // power-of-two partial count that fits in ws (ideally == NBLK)
    int npart = 1;
    while (npart * 2 <= NBLK && (size_t)(npart * 2) * sizeof(double) <= ws_size) npart *= 2;

    const int init_blocks = (NODES * NE + TPB - 1) / TPB;
    hipLaunchKernelGGL(init_kernel, dim3(init_blocks), dim3(TPB), 0, stream,
                       activate, out, ws, npart);
    hipLaunchKernelGGL(main_kernel, dim3(NBLK), dim3(TPB), 0, stream,
                       tag_table, node_tables, pos_node, pos_tag, neg_node, neg_tag,
                       out, ws, npart);
    hipLaunchKernelGGL(final_kernel, dim3(1), dim3(TPB), 0, stream, ws, out, npart);
}

// Round 2
// 96.145 us; speedup vs baseline: 1.0906x; 1.0906x over previous
//
#include <hip/hip_runtime.h>

#define NODES 100000
#define NTAG  10000
#define NE    4
#define ND    32
#define NB    524288

constexpr int TPB  = 256;              // threads per block
constexpr int NBLK = 2048;             // main-kernel blocks (exactly fills 256 CUs at 8 blocks/CU)
constexpr int GPB  = TPB / 8;          // 32 sample-groups per block (8 lanes per sample)
constexpr int NGRP = NBLK * GPB;       // 65536 groups
constexpr int ITER = (2 * NB) / NGRP;  // 16 samples per group (exact)

// ---- init: copy activate into out[1..], zero ws partials --------------------
__global__ __launch_bounds__(TPB) void init_kernel(const float* __restrict__ act,
                                                   float* __restrict__ out,
                                                   double* __restrict__ ws, int npart) {
    int i = blockIdx.x * TPB + threadIdx.x;
    if (i < NODES * NE) out[1 + i] = act[i];
    if (i < npart)      ws[i] = 0.0;
}

// ---- main: dists, argmin, scatter, loss partials ---------------------------
// Software-pipelined: indices prefetched 2 iters ahead, rows 1 iter ahead.
__global__ __launch_bounds__(TPB) void main_kernel(
    const float* __restrict__ tag_table, const float* __restrict__ node_tables,
    const int* __restrict__ pos_node, const int* __restrict__ pos_tag,
    const int* __restrict__ neg_node, const int* __restrict__ neg_tag,
    float* __restrict__ out, double* __restrict__ ws, int npart)
{
    const int g    = threadIdx.x & 7;   // lane within 8-lane sample group
    const int grp  = threadIdx.x >> 3;  // group id within block
    const uint32_t goff = (uint32_t)g << 4;  // byte offset of this lane's float4 in a 128B row

    const char* tagb  = (const char*)tag_table;
    const char* nodb0 = (const char*)node_tables;
    const char* nodb1 = nodb0 + (size_t)NODES * 128;
    const char* nodb2 = nodb1 + (size_t)NODES * 128;
    const char* nodb3 = nodb2 + (size_t)NODES * 128;

    const int s0 = blockIdx.x * GPB + grp;

    // 3-slot rotating index state (slot = k % 3), prefetched 2 ahead
    uint32_t no[3], to[3], ao[3];
    bool     pp[3];

    auto load_idx = [&](int k) {
        const int slot = k % 3;
        const int s = s0 + k * NGRP;
        const bool is_pos = s < NB;
        const int b    = is_pos ? s : s - NB;
        const int node = is_pos ? pos_node[b] : neg_node[b];
        const int tag  = is_pos ? pos_tag[b]  : neg_tag[b];
        no[slot] = ((uint32_t)node << 7) + goff;  // byte offset into a node plane
        to[slot] = ((uint32_t)tag  << 7) + goff;  // byte offset into tag table
        ao[slot] = (uint32_t)node << 2;           // element offset of activate row
        pp[slot] = is_pos;
    };

    load_idx(0);
    load_idx(1);

    // preload rows for iteration 0
    float4 ct  = *(const float4*)(tagb  + to[0]);
    float4 cr0 = *(const float4*)(nodb0 + no[0]);
    float4 cr1 = *(const float4*)(nodb1 + no[0]);
    float4 cr2 = *(const float4*)(nodb2 + no[0]);
    float4 cr3 = *(const float4*)(nodb3 + no[0]);

    float local = 0.f;

    #pragma unroll
    for (int k = 0; k < ITER; ++k) {
        const int cs = k % 3;

        // issue next iteration's row gathers (idx already resident)
        float4 nt{}, nr0{}, nr1{}, nr2{}, nr3{};
        if (k + 1 < ITER) {
            const int ns = (k + 1) % 3;
            nt  = *(const float4*)(tagb  + to[ns]);
            nr0 = *(const float4*)(nodb0 + no[ns]);
            nr1 = *(const float4*)(nodb1 + no[ns]);
            nr2 = *(const float4*)(nodb2 + no[ns]);
            nr3 = *(const float4*)(nodb3 + no[ns]);
        }
        // prefetch indices 2 ahead (into the retiring slot)
        if (k + 2 < ITER) load_idx(k + 2);

        // ---- compute current sample (fp64 dots: must match numpy argmin) ----
        const double tx = (double)ct.x, ty = (double)ct.y, tz = (double)ct.z, tw = (double)ct.w;
        double q0 = (double)cr0.x*tx + (double)cr0.y*ty + (double)cr0.z*tz + (double)cr0.w*tw;
        double q1 = (double)cr1.x*tx + (double)cr1.y*ty + (double)cr1.z*tz + (double)cr1.w*tw;
        double q2 = (double)cr2.x*tx + (double)cr2.y*ty + (double)cr2.z*tz + (double)cr2.w*tw;
        double q3 = (double)cr3.x*tx + (double)cr3.y*ty + (double)cr3.z*tz + (double)cr3.w*tw;

        #pragma unroll
        for (int off = 1; off < 8; off <<= 1) {   // xor 1,2,4 -> DPP lane ops
            q0 += __shfl_xor(q0, off, 64);
            q1 += __shfl_xor(q1, off, 64);
            q2 += __shfl_xor(q2, off, 64);
            q3 += __shfl_xor(q3, off, 64);
        }

        // dist_e = -q_e; argmin(dist) first-occurrence == strict "q_e > best"
        double best = q0; int idx = 0;
        if (q1 > best) { best = q1; idx = 1; }
        if (q2 > best) { best = q2; idx = 2; }
        if (q3 > best) { best = q3; idx = 3; }

        // pos term: softplus(dist), neg term: softplus(-dist); dist = -best
        const float x = pp[cs] ? (float)(-best) : (float)best;
        const float e = __expf(-fabsf(x));
        local += fmaxf(x, 0.f) + __logf(1.f + e);   // all 8 lanes add; /8 later

        if (pp[cs] && g == 0) atomicAdd(out + 1 + ao[cs] + idx, 1.0f);

        // rotate rows
        if (k + 1 < ITER) { ct = nt; cr0 = nr0; cr1 = nr1; cr2 = nr2; cr3 = nr3; }
    }

    // wave butterfly over all 64 lanes (each sample counted 8x -> scale 1/8)
    #pragma unroll
    for (int off = 1; off < 64; off <<= 1) local += __shfl_xor(local, off, 64);

    __shared__ double sm[TPB / 64];
    if ((threadIdx.x & 63) == 0) sm[threadIdx.x >> 6] = (double)local;
    __syncthreads();
    if (threadIdx.x == 0) {
        double tot = 0.0;
        #pragma unroll
        for (int w = 0; w < TPB / 64; ++w) tot += sm[w];
        atomicAdd(&ws[blockIdx.x & (npart - 1)], tot * 0.125);
    }
}

// ---- final: reduce ws partials into out[0] ---------------------------------
__global__ __launch_bounds__(TPB) void final_kernel(const double* __restrict__ ws,
                                                    float* __restrict__ out, int npart) {
    __shared__ double sm[TPB];
    double v = 0.0;
    for (int i = threadIdx.x; i < npart; i += TPB) v += ws[i];
    sm[threadIdx.x] = v;
    __syncthreads();
    for (int s = TPB / 2; s > 0; s >>= 1) {
        if (threadIdx.x < s) sm[threadIdx.x] += sm[threadIdx.x + s];
        __syncthreads();
    }
    if (threadIdx.x == 0) out[0] = (float)sm[0];
}

extern "C" void kernel_launch(void* const* d_in, const int* in_sizes, int n_in,
                              void* d_out, int out_size, void* d_ws, size_t ws_size,
                              hipStream_t stream) {
    const float* tag_table   = (const float*)d_in[0];
    const float* node_tables = (const float*)d_in[1];
    const float* activate    = (const float*)d_in[2];
    const int*   pos_node    = (const int*)d_in[3];
    const int*   pos_tag     = (const int*)d_in[4];
    const int*   neg_node    = (const int*)d_in[5];
    const int*   neg_tag     = (const int*)d_in[6];
    float*  out = (float*)d_out;
    double* ws  = (double*)d_ws;

    int npart = 1;
    while (npart * 2 <= NBLK && (size_t)(npart * 2) * sizeof(double) <= ws_size) npart *= 2;

    const int init_blocks = (NODES * NE + TPB - 1) / TPB;
    hipLaunchKernelGGL(init_kernel, dim3(init_blocks), dim3(TPB), 0, stream,
                       activate, out, ws, npart);
    hipLaunchKernelGGL(main_kernel, dim3(NBLK), dim3(TPB), 0, stream,
                       tag_table, node_tables, pos_node, pos_tag, neg_node, neg_tag,
                       out, ws, npart);
    hipLaunchKernelGGL(final_kernel, dim3(1), dim3(TPB), 0, stream, ws, out, npart);
}

// Round 3
// 87.438 us; speedup vs baseline: 1.1992x; 1.0996x over previous
//
#include <hip/hip_runtime.h>

#define NODES 100000
#define NTAG  10000
#define NE    4
#define ND    32
#define NB    524288

constexpr int TPB  = 256;            // threads per block
constexpr int NBLK = 2048;           // 8 blocks/CU on 256 CUs
constexpr int GPB  = TPB / 8;        // 32 sample-groups per block (8 lanes each)
constexpr int NSTR = NBLK / 8;       // 256 stripes; 8 consecutive blocks share a stripe
constexpr int SPS  = 2 * NB / NSTR;  // 4096 samples per stripe (stripe 0..127 pos, 128..255 neg)
constexpr int LCAP = 2048;           // LDS queue cap; Binom(4096,1/8): mean 512, sd 21 -> 2048 is 73 sigma

// ---- init: copy activate into out[1..], zero ws partials --------------------
__global__ __launch_bounds__(TPB) void init_kernel(const float* __restrict__ act,
                                                   float* __restrict__ out,
                                                   double* __restrict__ ws, int npart) {
    int i = blockIdx.x * TPB + threadIdx.x;
    if (i < NODES * NE) out[1 + i] = act[i];
    if (i < npart)      ws[i] = 0.0;
}

// ---- main: XCD-routed scan + gather + fp64 dots + argmin + loss ------------
__global__ __launch_bounds__(TPB) void main_kernel(
    const float* __restrict__ tag_table, const float* __restrict__ node_tables,
    const int* __restrict__ pos_node, const int* __restrict__ pos_tag,
    const int* __restrict__ neg_node, const int* __restrict__ neg_tag,
    float* __restrict__ out, double* __restrict__ ws, int npart)
{
    __shared__ uint32_t list[LCAP];
    __shared__ int cnt;
    __shared__ double sm[TPB / 64];

    const int tid  = threadIdx.x;
    const int g    = tid & 7;                    // lane within 8-lane sample group
    const int grp  = tid >> 3;                   // group id within block
    const uint32_t goff = (uint32_t)g << 4;      // byte offset of lane's float4 in a 128B row

    const int stripe = blockIdx.x >> 3;          // 8 consecutive blocks share a stripe
    const int xg     = blockIdx.x & 7;           // node-range group (== XCD if round-robin holds)
    const bool is_pos = stripe < (NSTR / 2);     // NB == 128*SPS: no stripe straddles pos/neg
    const int base = is_pos ? stripe * SPS : stripe * SPS - NB;
    const int* __restrict__ nsrc = is_pos ? pos_node : neg_node;
    const int* __restrict__ tsrc = is_pos ? pos_tag  : neg_tag;

    // ---- phase A: scan stripe, enqueue samples in my node range ----
    if (tid == 0) cnt = 0;
    __syncthreads();
    for (int i = tid; i < SPS; i += TPB) {
        const int node = nsrc[base + i];          // coalesced 256-wide
        if (node / 12500 == xg) {
            const int tag = tsrc[base + i];
            const int p = atomicAdd(&cnt, 1);
            list[p] = ((uint32_t)node << 14) | (uint32_t)tag;  // node<2^17, tag<2^14
        }
    }
    __syncthreads();
    const int n = cnt;

    // ---- phase B: process queue, 1 sample per 8-lane group, rows prefetched 1 ahead ----
    const char* tagb  = (const char*)tag_table;
    const char* nodb0 = (const char*)node_tables;
    const char* nodb1 = nodb0 + (size_t)NODES * 128;
    const char* nodb2 = nodb1 + (size_t)NODES * 128;
    const char* nodb3 = nodb2 + (size_t)NODES * 128;

    float local = 0.f;
    int j = grp;
    float4 ct, cr0, cr1, cr2, cr3;
    uint32_t cao = 0;

    if (j < n) {
        const uint32_t e = list[j];
        const uint32_t node = e >> 14, tag = e & 0x3FFFu;
        const uint32_t no = (node << 7) + goff, to = (tag << 7) + goff;
        cao = node << 2;
        ct  = *(const float4*)(tagb  + to);
        cr0 = *(const float4*)(nodb0 + no);
        cr1 = *(const float4*)(nodb1 + no);
        cr2 = *(const float4*)(nodb2 + no);
        cr3 = *(const float4*)(nodb3 + no);
    }

    while (j < n) {
        const int nj = j + GPB;
        float4 nt{}, nr0{}, nr1{}, nr2{}, nr3{};
        uint32_t nao = 0;
        if (nj < n) {                             // issue next sample's gathers early
            const uint32_t e = list[nj];
            const uint32_t node = e >> 14, tag = e & 0x3FFFu;
            const uint32_t no = (node << 7) + goff, to = (tag << 7) + goff;
            nao = node << 2;
            nt  = *(const float4*)(tagb  + to);
            nr0 = *(const float4*)(nodb0 + no);
            nr1 = *(const float4*)(nodb1 + no);
            nr2 = *(const float4*)(nodb2 + no);
            nr3 = *(const float4*)(nodb3 + no);
        }

        // fp64 dots of fp32 products: reproduces numpy argmin exactly (absmax 0 in r1/r2)
        const double tx = (double)ct.x, ty = (double)ct.y, tz = (double)ct.z, tw = (double)ct.w;
        double q0 = (double)cr0.x*tx + (double)cr0.y*ty + (double)cr0.z*tz + (double)cr0.w*tw;
        double q1 = (double)cr1.x*tx + (double)cr1.y*ty + (double)cr1.z*tz + (double)cr1.w*tw;
        double q2 = (double)cr2.x*tx + (double)cr2.y*ty + (double)cr2.z*tz + (double)cr2.w*tw;
        double q3 = (double)cr3.x*tx + (double)cr3.y*ty + (double)cr3.z*tz + (double)cr3.w*tw;

        #pragma unroll
        for (int off = 1; off < 8; off <<= 1) {   // xor 1,2,4: stays inside the 8-lane group
            q0 += __shfl_xor(q0, off, 64);
            q1 += __shfl_xor(q1, off, 64);
            q2 += __shfl_xor(q2, off, 64);
            q3 += __shfl_xor(q3, off, 64);
        }

        // dist_e = -q_e; argmin(dist) first-occurrence == strict "q_e > best"
        double best = q0; int idx = 0;
        if (q1 > best) { best = q1; idx = 1; }
        if (q2 > best) { best = q2; idx = 2; }
        if (q3 > best) { best = q3; idx = 3; }

        // pos: softplus(dist); neg: softplus(-dist); dist = -best
        const float x = is_pos ? (float)(-best) : (float)best;
        const float e = __expf(-fabsf(x));
        local += fmaxf(x, 0.f) + __logf(1.f + e);   // all 8 lanes add; /8 at the end

        if (is_pos && g == 0) atomicAdd(out + 1 + cao + idx, 1.0f);

        j = nj;
        ct = nt; cr0 = nr0; cr1 = nr1; cr2 = nr2; cr3 = nr3; cao = nao;
    }

    // 64-lane butterfly (each sample counted 8x -> scale 1/8)
    #pragma unroll
    for (int off = 1; off < 64; off <<= 1) local += __shfl_xor(local, off, 64);

    if ((tid & 63) == 0) sm[tid >> 6] = (double)local;
    __syncthreads();
    if (tid == 0) {
        double tot = 0.0;
        #pragma unroll
        for (int w = 0; w < TPB / 64; ++w) tot += sm[w];
        atomicAdd(&ws[blockIdx.x & (npart - 1)], tot * 0.125);
    }
}

// ---- final: reduce ws partials into out[0] ---------------------------------
__global__ __launch_bounds__(TPB) void final_kernel(const double* __restrict__ ws,
                                                    float* __restrict__ out, int npart) {
    __shared__ double sm[TPB];
    double v = 0.0;
    for (int i = threadIdx.x; i < npart; i += TPB) v += ws[i];
    sm[threadIdx.x] = v;
    __syncthreads();
    for (int s = TPB / 2; s > 0; s >>= 1) {
        if (threadIdx.x < s) sm[threadIdx.x] += sm[threadIdx.x + s];
        __syncthreads();
    }
    if (threadIdx.x == 0) out[0] = (float)sm[0];
}

extern "C" void kernel_launch(void* const* d_in, const int* in_sizes, int n_in,
                              void* d_out, int out_size, void* d_ws, size_t ws_size,
                              hipStream_t stream) {
    const float* tag_table   = (const float*)d_in[0];
    const float* node_tables = (const float*)d_in[1];
    const float* activate    = (const float*)d_in[2];
    const int*   pos_node    = (const int*)d_in[3];
    const int*   pos_tag     = (const int*)d_in[4];
    const int*   neg_node    = (const int*)d_in[5];
    const int*   neg_tag     = (const int*)d_in[6];
    float*  out = (float*)d_out;
    double* ws  = (double*)d_ws;

    int npart = 1;
    while (npart * 2 <= NBLK && (size_t)(npart * 2) * sizeof(double) <= ws_size) npart *= 2;

    const int init_blocks = (NODES * NE + TPB - 1) / TPB;
    hipLaunchKernelGGL(init_kernel, dim3(init_blocks), dim3(TPB), 0, stream,
                       activate, out, ws, npart);
    hipLaunchKernelGGL(main_kernel, dim3(NBLK), dim3(TPB), 0, stream,
                       tag_table, node_tables, pos_node, pos_tag, neg_node, neg_tag,
                       out, ws, npart);
    hipLaunchKernelGGL(final_kernel, dim3(1), dim3(TPB), 0, stream, ws, out, npart);
}